// Round 1
// baseline (1534.114 us; speedup 1.0000x reference)
//
#include <hip/hip_runtime.h>

#define HW   128
#define OHW  256
#define G0n  64
#define HID  256
#define NOUT 1728   // 9*64*3
#define NB   4

// ---------------- Kernel 1: 5x5 SAME conv + bias + ReLU -> feat[n][g][h][w] ----------------
__global__ __launch_bounds__(256) void conv5_relu_kernel(
    const float* __restrict__ x, const float* __restrict__ cw,
    const float* __restrict__ cb, float* __restrict__ feat)
{
    int idx = blockIdx.x * 256 + threadIdx.x;       // ((n*64+g)*128+h)*128+w
    int w = idx & 127;
    int h = (idx >> 7) & 127;
    int g = (idx >> 14) & 63;
    int n = idx >> 20;
    float acc = cb[g];
    #pragma unroll
    for (int ci = 0; ci < 3; ++ci) {
        const float* xp = x + (n * 3 + ci) * (HW * HW);
        const float* wp = cw + ((g * 3 + ci) * 5) * 5;
        #pragma unroll
        for (int ki = 0; ki < 5; ++ki) {
            int hh = h + ki - 2;
            if (hh < 0 || hh >= HW) continue;
            #pragma unroll
            for (int kj = 0; kj < 5; ++kj) {
                int ww = w + kj - 2;
                if (ww < 0 || ww >= HW) continue;
                acc = fmaf(xp[hh * HW + ww], wp[ki * 5 + kj], acc);
            }
        }
    }
    feat[idx] = fmaxf(acc, 0.0f);
}

// ---------------- Kernel 2: fused Pos2Weight GEMM + dynamic conv + mean-shift ----------------
// Block = 256 threads, owns an 8x8 tile of OUTPUT pixels (oy0..+7, ox0..+7).
// lw[r, col] = relu(pos[r] @ w1 + b1) @ w2 + b2 computed in 96-col chunks,
// immediately contracted with unfold(feat) cols.
__global__ __launch_bounds__(256) void fused_metasr_kernel(
    const float* __restrict__ feat, const float* __restrict__ pos,
    const float* __restrict__ w1, const float* __restrict__ b1,
    const float* __restrict__ w2, const float* __restrict__ b2,
    float* __restrict__ out)
{
    __shared__ float Ahid[64][257];          // hidden activations, 64 px x 256 (pad->bank spread)
    __shared__ float Bw2[64][96];            // w2 K-subtile (64 k) x N-chunk (96 cols)
    __shared__ float lwc[64][97];            // lw chunk 64 px x 96 cols (padded)
    __shared__ float ftile[64][6][6][4];     // [ci][row][col][n], 3x3-halo feat tile

    int tid = threadIdx.x;
    int bx = blockIdx.x & 31, by = blockIdx.x >> 5;
    int oy0 = by * 8, ox0 = bx * 8;          // output tile origin
    int h0 = by * 4, w0 = bx * 4;            // input (low-res) tile origin

    // ---- stage feat halo tile (rows h0-1..h0+4, cols w0-1..w0+4, zero-padded) ----
    for (int i = tid; i < 64 * 6 * 6 * 4; i += 256) {
        int n = i & 3;
        int t2 = i >> 2;
        int c = t2 % 6;
        int t3 = t2 / 6;
        int r = t3 % 6;
        int ci = t3 / 6;
        int gh = h0 - 1 + r, gw = w0 - 1 + c;
        float v = 0.0f;
        if (gh >= 0 && gh < HW && gw >= 0 && gw < HW)
            v = feat[((n * G0n + ci) * HW + gh) * HW + gw];
        ftile[ci][r][c][n] = v;
    }

    // ---- compute hidden = relu(pos @ w1 + b1) for the 64 pixels of this tile ----
    {
        int px = tid >> 2;                   // 0..63
        int ks = (tid & 3) * 64;             // this thread's k range
        int py = px >> 3, pxx = px & 7;
        int rr = (oy0 + py) * OHW + (ox0 + pxx);
        float p0 = pos[rr * 3 + 0], p1 = pos[rr * 3 + 1], p2 = pos[rr * 3 + 2];
        for (int k = ks; k < ks + 64; ++k) {
            float hsum = fmaf(p0, w1[k], fmaf(p1, w1[HID + k], fmaf(p2, w1[2 * HID + k], b1[k])));
            Ahid[px][k] = fmaxf(hsum, 0.0f);
        }
    }
    __syncthreads();

    int pxg = tid >> 4;                      // GEMM role: 16 pixel-groups of 4
    int colg = tid & 15;                     //            16 col-groups of 6
    int epx = tid >> 2, en = tid & 3;        // einsum role: (pixel, batch)
    int eih = (epx >> 3) >> 1;               // input-row within tile (0..3)
    int eiw = (epx & 7) >> 1;                // input-col within tile (0..3)
    float oacc0 = 0.0f, oacc1 = 0.0f, oacc2 = 0.0f;

    for (int ch = 0; ch < 18; ++ch) {        // 18 chunks x 96 cols = 1728
        int c0 = ch * 96;
        float acc[4][6];
        #pragma unroll
        for (int j = 0; j < 6; ++j) {
            float bv = b2[c0 + colg * 6 + j];
            #pragma unroll
            for (int i = 0; i < 4; ++i) acc[i][j] = bv;
        }
        for (int kc = 0; kc < 4; ++kc) {     // K = 256 in 4 sub-tiles of 64
            __syncthreads();
            #pragma unroll
            for (int i = 0; i < 6; ++i) {    // stage w2[kc*64..+63][c0..c0+95]
                int fi = tid + i * 256;      // 1536 float4s
                int row = fi / 24;
                int col = (fi % 24) * 4;
                *(float4*)&Bw2[row][col] =
                    *(const float4*)&w2[(kc * 64 + row) * NOUT + c0 + col];
            }
            __syncthreads();
            #pragma unroll 16
            for (int kk = 0; kk < 64; ++kk) {
                int k = kc * 64 + kk;
                float a0 = Ahid[pxg * 4 + 0][k];
                float a1 = Ahid[pxg * 4 + 1][k];
                float a2 = Ahid[pxg * 4 + 2][k];
                float a3 = Ahid[pxg * 4 + 3][k];
                const float2* bp = (const float2*)&Bw2[kk][colg * 6];
                float2 b01 = bp[0], b23 = bp[1], b45 = bp[2];
                float b[6] = {b01.x, b01.y, b23.x, b23.y, b45.x, b45.y};
                float a[4] = {a0, a1, a2, a3};
                #pragma unroll
                for (int i = 0; i < 4; ++i)
                    #pragma unroll
                    for (int j = 0; j < 6; ++j)
                        acc[i][j] = fmaf(a[i], b[j], acc[i][j]);
            }
        }
        __syncthreads();
        #pragma unroll
        for (int i = 0; i < 4; ++i)
            #pragma unroll
            for (int j = 0; j < 6; ++j)
                lwc[pxg * 4 + i][colg * 6 + j] = acc[i][j];
        __syncthreads();

        // ---- einsum partial: k in [ch*32, ch*32+32) ----
        int k0 = ch * 32;
        #pragma unroll 8
        for (int kk = 0; kk < 32; ++kk) {
            int k = k0 + kk;
            int ci = k / 9;
            int r9 = k - ci * 9;
            int di = r9 / 3;
            int dj = r9 - di * 3;
            float f = ftile[ci][eih + di][eiw + dj][en];
            oacc0 = fmaf(f, lwc[epx][kk * 3 + 0], oacc0);
            oacc1 = fmaf(f, lwc[epx][kk * 3 + 1], oacc1);
            oacc2 = fmaf(f, lwc[epx][kk * 3 + 2], oacc2);
        }
    }

    // ---- write output + mean shift ----
    int py = epx >> 3, pxx = epx & 7;
    int oy = oy0 + py, ox = ox0 + pxx;
    out[((en * 3 + 0) * OHW + oy) * OHW + ox] = oacc0 + 0.4488f * 255.0f;
    out[((en * 3 + 1) * OHW + oy) * OHW + ox] = oacc1 + 0.4371f * 255.0f;
    out[((en * 3 + 2) * OHW + oy) * OHW + ox] = oacc2 + 0.4040f * 255.0f;
}

extern "C" void kernel_launch(void* const* d_in, const int* in_sizes, int n_in,
                              void* d_out, int out_size, void* d_ws, size_t ws_size,
                              hipStream_t stream) {
    (void)in_sizes; (void)n_in; (void)out_size; (void)ws_size;
    const float* x      = (const float*)d_in[0];
    const float* posm   = (const float*)d_in[1];
    const float* conv_w = (const float*)d_in[2];
    const float* conv_b = (const float*)d_in[3];
    const float* w1     = (const float*)d_in[4];
    const float* b1     = (const float*)d_in[5];
    const float* w2     = (const float*)d_in[6];
    const float* b2     = (const float*)d_in[7];
    float* out  = (float*)d_out;
    float* feat = (float*)d_ws;              // 4*64*128*128 floats = 16.8 MB

    conv5_relu_kernel<<<(NB * G0n * HW * HW) / 256, 256, 0, stream>>>(x, conv_w, conv_b, feat);
    fused_metasr_kernel<<<(OHW / 8) * (OHW / 8), 256, 0, stream>>>(
        feat, posm, w1, b1, w2, b2, out);
}

// Round 2
// 307.908 us; speedup vs baseline: 4.9824x; 4.9824x over previous
//
#include <hip/hip_runtime.h>

#define HW   128
#define OHW  256
#define G0n  64
#define HID  256
#define NOUT 1728
#define NB   4

typedef __attribute__((ext_vector_type(8))) short bf16x8;
typedef __attribute__((ext_vector_type(4))) float f32x4;
typedef __attribute__((ext_vector_type(4))) unsigned int u32x4;
typedef __attribute__((ext_vector_type(2))) unsigned int u32x2;

__device__ __forceinline__ unsigned short f2bf(float f) {
    unsigned int u = __builtin_bit_cast(unsigned int, f);
    u += 0x7fffu + ((u >> 16) & 1u);
    return (unsigned short)(u >> 16);
}
__device__ __forceinline__ float bflo(unsigned int d) {
    return __builtin_bit_cast(float, d << 16);
}
__device__ __forceinline__ float bfhi(unsigned int d) {
    return __builtin_bit_cast(float, d & 0xffff0000u);
}

// ---------------- Kernel 0: w2 [256][1728] f32 -> w2t [1728][256] bf16 ----------------
__global__ __launch_bounds__(256) void prep_w2t(const float* __restrict__ w2,
                                                unsigned short* __restrict__ w2t) {
    int idx = blockIdx.x * 256 + threadIdx.x;   // col*256 + k
    int k = idx & 255, col = idx >> 8;
    w2t[idx] = f2bf(w2[k * NOUT + col]);
}

// ---------------- Kernel 1: 5x5 SAME conv + bias + ReLU ----------------
__global__ __launch_bounds__(256) void conv5_relu_kernel(
    const float* __restrict__ x, const float* __restrict__ cw,
    const float* __restrict__ cb, float* __restrict__ feat)
{
    int idx = blockIdx.x * 256 + threadIdx.x;   // ((n*64+g)*128+h)*128+w
    int w = idx & 127;
    int h = (idx >> 7) & 127;
    int g = (idx >> 14) & 63;
    int n = idx >> 20;
    float acc = cb[g];
    #pragma unroll
    for (int ci = 0; ci < 3; ++ci) {
        const float* xp = x + (n * 3 + ci) * (HW * HW);
        const float* wp = cw + ((g * 3 + ci) * 5) * 5;
        #pragma unroll
        for (int ki = 0; ki < 5; ++ki) {
            int hh = h + ki - 2;
            if (hh < 0 || hh >= HW) continue;
            #pragma unroll
            for (int kj = 0; kj < 5; ++kj) {
                int ww = w + kj - 2;
                if (ww < 0 || ww >= HW) continue;
                acc = fmaf(xp[hh * HW + ww], wp[ki * 5 + kj], acc);
            }
        }
    }
    feat[idx] = fmaxf(acc, 0.0f);
}

// ---------------- Kernel 2: fused MFMA Pos2Weight GEMM + dynamic conv + mean-shift ----
// Block: 512 threads (8 waves, 2M x 4N), M = 128 output pixels (16x8 tile).
// A = hidden [128][256] bf16 in registers; B = w2t chunk staged in LDS;
// lw chunk written to LDS bf16, consumed by einsum against bf16 feat tile.
__global__ __launch_bounds__(512, 2) void fused_metasr_mfma(
    const float* __restrict__ feat, const unsigned short* __restrict__ w2t,
    const float* __restrict__ pos,  const float* __restrict__ w1,
    const float* __restrict__ b1,   const float* __restrict__ b2,
    float* __restrict__ out)
{
    __shared__ __align__(16) unsigned short Bs[192 * 132];      // 50688 B  [col][k128+pad]
    __shared__ __align__(16) unsigned short AL[128 * 264];      // 67584 B  Ahid ∪ lwc
    __shared__ __align__(16) unsigned short FT[64 * 10 * 4 * 8];// 40960 B  [ci][r][n][c8]

    const int tid = threadIdx.x;
    const int bx = blockIdx.x & 31, by = blockIdx.x >> 5;
    const int oy0 = by * 16, ox0 = bx * 8;
    const int h0 = by * 8,  w0 = bx * 4;

    // ---- stage feat halo tile as bf16: FT[ci][r10][n4][c8] ----
    for (int i = tid; i < 64 * 10 * 4 * 8; i += 512) {
        int c  = i & 7;
        int n  = (i >> 3) & 3;
        int r  = (i >> 5) % 10;
        int ci = i / 320;
        int gh = h0 - 1 + r, gw = w0 - 1 + c;
        float v = 0.0f;
        if (c < 6 && gh >= 0 && gh < HW && gw >= 0 && gw < HW)
            v = feat[((n * G0n + ci) * HW + gh) * HW + gw];
        FT[i] = f2bf(v);
    }

    // ---- hidden = relu(pos @ w1 + b1) -> AL (as Ahid[px][256] bf16) ----
    {
        int px = tid >> 2, kq = (tid & 3) << 6;
        int rr = (oy0 + (px >> 3)) * OHW + (ox0 + (px & 7));
        float p0 = pos[rr * 3 + 0], p1 = pos[rr * 3 + 1], p2 = pos[rr * 3 + 2];
        for (int k = kq; k < kq + 64; ++k) {
            float h = fmaf(p0, w1[k], fmaf(p1, w1[HID + k], fmaf(p2, w1[2 * HID + k], b1[k])));
            AL[px * 264 + k] = f2bf(fmaxf(h, 0.0f));
        }
    }
    __syncthreads();

    // ---- load A fragments (once) ----
    const int lane = tid & 63, wid = tid >> 6;
    const int mh = wid >> 2, nq = wid & 3;
    const int cl = lane & 15, hi = lane >> 4;
    bf16x8 afrag[4][8];
    #pragma unroll
    for (int m = 0; m < 4; ++m)
        #pragma unroll
        for (int k8 = 0; k8 < 8; ++k8) {
            int row = mh * 64 + m * 16 + cl;
            afrag[m][k8] = *(const bf16x8*)&AL[row * 264 + k8 * 32 + hi * 8];
        }

    // einsum thread roles
    const int epx = tid >> 2, en = tid & 3;
    const int eiy = epx >> 4;
    const int eix = (epx & 7) >> 1;
    const bool selhi = (eix >= 2);
    const bool podd  = (eix & 1) != 0;
    const int fbase = eiy * 64 + en * 16;
    const unsigned lwbase = (unsigned)(epx * 528);
    float oacc0 = 0.f, oacc1 = 0.f, oacc2 = 0.f;

    for (int ch = 0; ch < 9; ++ch) {
        f32x4 acc[4][3];
        #pragma unroll
        for (int m = 0; m < 4; ++m)
            #pragma unroll
            for (int j = 0; j < 3; ++j)
                acc[m][j] = (f32x4){0.f, 0.f, 0.f, 0.f};

        #pragma unroll
        for (int kh = 0; kh < 2; ++kh) {
            __syncthreads();   // prev readers of Bs / AL done
            // stage B: cols ch*192..+191, k kh*128..+127 (48 KB)
            #pragma unroll
            for (int s = 0; s < 6; ++s) {
                int seg = s * 512 + tid;
                int col = seg >> 4, off = seg & 15;
                u32x4 v = *(const u32x4*)(w2t + ((ch * 192 + col) << 8) + (kh << 7) + (off << 3));
                *(u32x4*)((char*)Bs + col * 264 + off * 16) = v;
            }
            __syncthreads();
            #pragma unroll
            for (int kk = 0; kk < 4; ++kk) {
                bf16x8 bfrag[3];
                #pragma unroll
                for (int j = 0; j < 3; ++j) {
                    int col = nq * 48 + j * 16 + cl;
                    bfrag[j] = *(const bf16x8*)((const char*)Bs + col * 264 + kk * 64 + hi * 16);
                }
                #pragma unroll
                for (int m = 0; m < 4; ++m)
                    #pragma unroll
                    for (int j = 0; j < 3; ++j)
                        acc[m][j] = __builtin_amdgcn_mfma_f32_16x16x32_bf16(
                            afrag[m][kh * 4 + kk], bfrag[j], acc[m][j], 0, 0, 0);
            }
        }

        // ---- C-write (+bias) into lwc (= AL): [px][kt][c4] bf16 ----
        #pragma unroll
        for (int j = 0; j < 3; ++j) {
            int col = nq * 48 + j * 16 + cl;
            float bv = b2[ch * 192 + col];
            int kt = col / 3;
            int c  = col - kt * 3;
            #pragma unroll
            for (int m = 0; m < 4; ++m)
                #pragma unroll
                for (int r = 0; r < 4; ++r) {
                    int row = mh * 64 + m * 16 + hi * 4 + r;
                    AL[row * 264 + kt * 4 + c] = f2bf(acc[m][j][r] + bv);
                }
        }
        __syncthreads();

        // ---- einsum partial: k in [ch*64, ch*64+64) ----
        int k0 = ch * 64;
        int t3a = k0 / 3;
        int t3b = (k0 + 63) / 3;
        auto do_t3 = [&](int t3, bool guard) {
            int ci = t3 / 3;
            int di = t3 - ci * 3;
            const char* fp = (const char*)FT + ci * 640 + di * 64 + fbase;
            u32x4 w = *(const u32x4*)fp;
            unsigned a0 = selhi ? w.y : w.x;
            unsigned b0 = selhi ? w.z : w.y;
            float loa = bflo(a0), hia = bfhi(a0);
            float lob = bflo(b0), hib = bfhi(b0);
            float f0 = podd ? hia : loa;
            float f1 = podd ? lob : hia;
            float f2 = podd ? hib : lob;
            int ktb = 3 * t3 - k0;
            #pragma unroll
            for (int dj = 0; dj < 3; ++dj) {
                int kt = ktb + dj;
                float fv = dj == 0 ? f0 : (dj == 1 ? f1 : f2);
                if (guard) {
                    fv = ((unsigned)kt < 64u) ? fv : 0.0f;
                    kt = kt < 0 ? 0 : (kt > 63 ? 63 : kt);
                }
                u32x2 d = *(const u32x2*)((const char*)AL + lwbase + (unsigned)(kt * 8));
                oacc0 = fmaf(fv, bflo(d.x), oacc0);
                oacc1 = fmaf(fv, bfhi(d.x), oacc1);
                oacc2 = fmaf(fv, bflo(d.y), oacc2);
            }
        };
        do_t3(t3a, true);
        for (int t3 = t3a + 1; t3 < t3b; ++t3) do_t3(t3, false);
        do_t3(t3b, true);
    }

    // ---- write output + mean shift ----
    int oy = oy0 + (epx >> 3), ox = ox0 + (epx & 7);
    out[((en * 3 + 0) * OHW + oy) * OHW + ox] = oacc0 + 0.4488f * 255.0f;
    out[((en * 3 + 1) * OHW + oy) * OHW + ox] = oacc1 + 0.4371f * 255.0f;
    out[((en * 3 + 2) * OHW + oy) * OHW + ox] = oacc2 + 0.4040f * 255.0f;
}

extern "C" void kernel_launch(void* const* d_in, const int* in_sizes, int n_in,
                              void* d_out, int out_size, void* d_ws, size_t ws_size,
                              hipStream_t stream) {
    (void)in_sizes; (void)n_in; (void)out_size; (void)ws_size;
    const float* x      = (const float*)d_in[0];
    const float* posm   = (const float*)d_in[1];
    const float* conv_w = (const float*)d_in[2];
    const float* conv_b = (const float*)d_in[3];
    const float* w1     = (const float*)d_in[4];
    const float* b1     = (const float*)d_in[5];
    const float* w2     = (const float*)d_in[6];
    const float* b2     = (const float*)d_in[7];
    float* out = (float*)d_out;

    unsigned short* w2t = (unsigned short*)d_ws;                 // 884736 B, 16B-aligned
    float* feat = (float*)((char*)d_ws + 884736);                // 16.8 MB

    prep_w2t<<<(NOUT * HID) / 256, 256, 0, stream>>>(w2, w2t);
    conv5_relu_kernel<<<(NB * G0n * HW * HW) / 256, 256, 0, stream>>>(x, conv_w, conv_b, feat);
    fused_metasr_mfma<<<512, 512, 0, stream>>>(feat, w2t, posm, w1, b1, b2, out);
}

// Round 3
// 235.059 us; speedup vs baseline: 6.5265x; 1.3099x over previous
//
#include <hip/hip_runtime.h>

#define HW   128
#define OHW  256
#define G0n  64
#define HID  256
#define NOUT 1728
#define NB   4

typedef __attribute__((ext_vector_type(8))) short bf16x8;
typedef __attribute__((ext_vector_type(4))) float f32x4;
typedef __attribute__((ext_vector_type(4))) unsigned int u32x4;
typedef __attribute__((ext_vector_type(2))) unsigned int u32x2;

__device__ __forceinline__ unsigned short f2bf(float f) {
    unsigned int u = __builtin_bit_cast(unsigned int, f);
    u += 0x7fffu + ((u >> 16) & 1u);
    return (unsigned short)(u >> 16);
}
__device__ __forceinline__ float bflo(unsigned int d) {
    return __builtin_bit_cast(float, d << 16);
}
__device__ __forceinline__ float bfhi(unsigned int d) {
    return __builtin_bit_cast(float, d & 0xffff0000u);
}

// ---------------- Kernel 0: w2 [256][1728] f32 -> w2t [1728][256] bf16 (LDS tiled) ----
__global__ __launch_bounds__(256) void prep_w2t(const float* __restrict__ w2,
                                                unsigned short* __restrict__ w2t) {
    __shared__ float t[64][65];
    int kb = blockIdx.x & 3, cb = blockIdx.x >> 2;     // 4 k-blocks x 27 col-blocks
    int lc = threadIdx.x & 63, lr = threadIdx.x >> 6;
    #pragma unroll
    for (int i = 0; i < 16; ++i) {
        int kk = lr + i * 4;
        t[kk][lc] = w2[(kb * 64 + kk) * NOUT + cb * 64 + lc];   // coalesced read
    }
    __syncthreads();
    #pragma unroll
    for (int i = 0; i < 16; ++i) {
        int cc = lr + i * 4;
        w2t[(cb * 64 + cc) * 256 + kb * 64 + lc] = f2bf(t[lc][cc]);  // coalesced write
    }
}

// ---------------- Kernel 1: 5x5 SAME conv + bias + ReLU, 4 outputs/thread ----------------
__global__ __launch_bounds__(256) void conv5_relu_kernel(
    const float* __restrict__ x, const float* __restrict__ cw,
    const float* __restrict__ cb, float* __restrict__ feat)
{
    int idx = blockIdx.x * 256 + threadIdx.x;   // ((n*64+g)*128+h)*32 + w4
    int w4 = (idx & 31) * 4;
    int h  = (idx >> 5) & 127;
    int g  = (idx >> 12) & 63;
    int n  = idx >> 18;
    float bv = cb[g];
    float a[4] = {bv, bv, bv, bv};
    const float* wp = cw + g * 75;
    #pragma unroll
    for (int ci = 0; ci < 3; ++ci) {
        const float* xr = x + (n * 3 + ci) * (HW * HW);
        #pragma unroll
        for (int ki = 0; ki < 5; ++ki) {
            int hh = h + ki - 2;
            if (hh < 0 || hh >= HW) continue;
            const float* row = xr + hh * HW;
            float f[8];
            if (w4 != 0 && w4 != 124) {
                float2 u0 = *(const float2*)(row + w4 - 2);
                float2 u1 = *(const float2*)(row + w4);
                float2 u2 = *(const float2*)(row + w4 + 2);
                float2 u3 = *(const float2*)(row + w4 + 4);
                f[0] = u0.x; f[1] = u0.y; f[2] = u1.x; f[3] = u1.y;
                f[4] = u2.x; f[5] = u2.y; f[6] = u3.x; f[7] = u3.y;
            } else {
                #pragma unroll
                for (int j = 0; j < 8; ++j) {
                    int ww = w4 - 2 + j;
                    f[j] = (ww >= 0 && ww < HW) ? row[ww] : 0.0f;
                }
            }
            float wt[5];
            #pragma unroll
            for (int kj = 0; kj < 5; ++kj) wt[kj] = wp[ci * 25 + ki * 5 + kj];
            #pragma unroll
            for (int j = 0; j < 4; ++j)
                #pragma unroll
                for (int kj = 0; kj < 5; ++kj)
                    a[j] = fmaf(f[j + kj], wt[kj], a[j]);
        }
    }
    float4 o;
    o.x = fmaxf(a[0], 0.f); o.y = fmaxf(a[1], 0.f);
    o.z = fmaxf(a[2], 0.f); o.w = fmaxf(a[3], 0.f);
    *(float4*)&feat[((n * G0n + g) * HW + h) * HW + w4] = o;
}

// ---------------- Kernel 2: fused MFMA Pos2Weight GEMM + dynamic conv + mean-shift ----
// 256 threads (4 waves = 4 N-quarters), M = 64 output pixels (8x8 tile).
// A (hidden) fully in registers; B frags read direct from L2-resident w2t.
// LDS: AL (Ahid -> lwc union) 33.3 KB + FT 24.6 KB = 57.9 KB -> 2 blocks/CU.
__global__ __launch_bounds__(256, 2) void fused_metasr_mfma(
    const float* __restrict__ feat, const unsigned short* __restrict__ w2t,
    const float* __restrict__ pos,  const float* __restrict__ w1,
    const float* __restrict__ b1,   const float* __restrict__ b2,
    float* __restrict__ out)
{
    __shared__ __align__(16) unsigned short AL[64 * 260];        // 33280 B
    __shared__ __align__(16) unsigned short FT[64 * 6 * 4 * 8];  // 24576 B [ci][r6][n4][c8]

    const int tid = threadIdx.x;
    const int bx = blockIdx.x & 31, by = blockIdx.x >> 5;
    const int oy0 = by * 8, ox0 = bx * 8;
    const int h0 = by * 4,  w0 = bx * 4;

    // ---- stage feat halo tile as bf16 ----
    for (int i = tid; i < 64 * 6 * 4 * 8; i += 256) {
        int c  = i & 7;
        int n  = (i >> 3) & 3;
        int r  = (i >> 5) % 6;
        int ci = (i >> 5) / 6;
        int gh = h0 - 1 + r, gw = w0 - 1 + c;
        float v = 0.0f;
        if (c < 6 && gh >= 0 && gh < HW && gw >= 0 && gw < HW)
            v = feat[((n * G0n + ci) * HW + gh) * HW + gw];
        FT[i] = f2bf(v);
    }

    // ---- hidden = relu(pos @ w1 + b1) -> AL[px][256], b64 writes, k-interleaved ----
    {
        int px = tid >> 2, q = tid & 3;
        int rr = (oy0 + (px >> 3)) * OHW + (ox0 + (px & 7));
        float p0 = pos[rr * 3 + 0], p1 = pos[rr * 3 + 1], p2 = pos[rr * 3 + 2];
        #pragma unroll
        for (int j = 0; j < 16; ++j) {
            int k0 = q * 4 + j * 16;
            float4 wa = *(const float4*)&w1[k0];
            float4 wb = *(const float4*)&w1[HID + k0];
            float4 wc = *(const float4*)&w1[2 * HID + k0];
            float4 bb = *(const float4*)&b1[k0];
            unsigned short h0s = f2bf(fmaxf(fmaf(p0, wa.x, fmaf(p1, wb.x, fmaf(p2, wc.x, bb.x))), 0.f));
            unsigned short h1s = f2bf(fmaxf(fmaf(p0, wa.y, fmaf(p1, wb.y, fmaf(p2, wc.y, bb.y))), 0.f));
            unsigned short h2s = f2bf(fmaxf(fmaf(p0, wa.z, fmaf(p1, wb.z, fmaf(p2, wc.z, bb.z))), 0.f));
            unsigned short h3s = f2bf(fmaxf(fmaf(p0, wa.w, fmaf(p1, wb.w, fmaf(p2, wc.w, bb.w))), 0.f));
            u32x2 pk;
            pk.x = (unsigned)h0s | ((unsigned)h1s << 16);
            pk.y = (unsigned)h2s | ((unsigned)h3s << 16);
            *(u32x2*)&AL[px * 260 + k0] = pk;
        }
    }
    __syncthreads();

    // ---- load A fragments once (identical across waves) ----
    const int lane = tid & 63, nq = tid >> 6;     // 4 waves = 4 N-quarters
    const int cl = lane & 15, hi = lane >> 4;
    bf16x8 afrag[4][8];
    #pragma unroll
    for (int m = 0; m < 4; ++m)
        #pragma unroll
        for (int k8 = 0; k8 < 8; ++k8)
            afrag[m][k8] = *(const bf16x8*)&AL[(m * 16 + cl) * 260 + k8 * 32 + hi * 8];

    // einsum thread roles
    const int epx = tid >> 2, en = tid & 3;
    const int iy = (epx >> 3) >> 1;
    const int ix = (epx & 7) >> 1;
    const bool selhi = (ix >= 2);
    const bool podd  = (ix & 1) != 0;
    const unsigned lwbase = (unsigned)(epx * 520);
    float oacc0 = 0.f, oacc1 = 0.f, oacc2 = 0.f;

    for (int ch = 0; ch < 9; ++ch) {
        f32x4 acc[4][3];
        #pragma unroll
        for (int m = 0; m < 4; ++m)
            #pragma unroll
            for (int j = 0; j < 3; ++j)
                acc[m][j] = (f32x4){0.f, 0.f, 0.f, 0.f};

        #pragma unroll
        for (int kh = 0; kh < 2; ++kh) {
            #pragma unroll
            for (int kk = 0; kk < 4; ++kk) {
                bf16x8 bfrag[3];
                #pragma unroll
                for (int j = 0; j < 3; ++j) {
                    int col = nq * 48 + j * 16 + cl;
                    bfrag[j] = *(const bf16x8*)&w2t[(ch * 192 + col) * 256 + kh * 128 + kk * 32 + hi * 8];
                }
                #pragma unroll
                for (int m = 0; m < 4; ++m)
                    #pragma unroll
                    for (int j = 0; j < 3; ++j)
                        acc[m][j] = __builtin_amdgcn_mfma_f32_16x16x32_bf16(
                            afrag[m][kh * 4 + kk], bfrag[j], acc[m][j], 0, 0, 0);
            }
        }

        __syncthreads();   // prev-chunk einsum readers (and initial afrag loads) done
        // ---- C-write (+bias) into lwc (= AL): [px][kt*4+c] bf16 ----
        #pragma unroll
        for (int j = 0; j < 3; ++j) {
            int col = nq * 48 + j * 16 + cl;
            float bv = b2[ch * 192 + col];
            int kt = col / 3;
            int c  = col - kt * 3;
            #pragma unroll
            for (int m = 0; m < 4; ++m)
                #pragma unroll
                for (int r = 0; r < 4; ++r) {
                    int row = m * 16 + hi * 4 + r;
                    AL[row * 260 + kt * 4 + c] = f2bf(acc[m][j][r] + bv);
                }
        }
        __syncthreads();

        // ---- einsum partial: kt in [0,64) of this chunk (k = ch*64 + kt) ----
        int k0 = ch * 64;
        int t3a = k0 / 3;
        int t3b = (k0 + 63) / 3;
        auto do_t3 = [&](int t3, bool guard) {
            int ci = t3 / 3;
            int di = t3 - ci * 3;
            const char* fp = (const char*)FT + ci * 384 + (iy + di) * 64 + en * 16;
            u32x4 w = *(const u32x4*)fp;
            unsigned a0 = selhi ? w.y : w.x;
            unsigned b0 = selhi ? w.z : w.y;
            float loa = bflo(a0), hia = bfhi(a0);
            float lob = bflo(b0), hib = bfhi(b0);
            float f0 = podd ? hia : loa;
            float f1 = podd ? lob : hia;
            float f2 = podd ? hib : lob;
            int ktb = 3 * t3 - k0;
            #pragma unroll
            for (int dj = 0; dj < 3; ++dj) {
                int kt = ktb + dj;
                float fv = dj == 0 ? f0 : (dj == 1 ? f1 : f2);
                if (guard) {
                    fv = ((unsigned)kt < 64u) ? fv : 0.0f;
                    kt = kt < 0 ? 0 : (kt > 63 ? 63 : kt);
                }
                u32x2 d = *(const u32x2*)((const char*)AL + lwbase + (unsigned)(kt * 8));
                oacc0 = fmaf(fv, bflo(d.x), oacc0);
                oacc1 = fmaf(fv, bfhi(d.x), oacc1);
                oacc2 = fmaf(fv, bflo(d.y), oacc2);
            }
        };
        do_t3(t3a, true);
        for (int t3 = t3a + 1; t3 < t3b; ++t3) do_t3(t3, false);
        do_t3(t3b, true);
    }

    // ---- write output + mean shift ----
    int oy = oy0 + (epx >> 3), ox = ox0 + (epx & 7);
    out[((en * 3 + 0) * OHW + oy) * OHW + ox] = oacc0 + 0.4488f * 255.0f;
    out[((en * 3 + 1) * OHW + oy) * OHW + ox] = oacc1 + 0.4371f * 255.0f;
    out[((en * 3 + 2) * OHW + oy) * OHW + ox] = oacc2 + 0.4040f * 255.0f;
}

extern "C" void kernel_launch(void* const* d_in, const int* in_sizes, int n_in,
                              void* d_out, int out_size, void* d_ws, size_t ws_size,
                              hipStream_t stream) {
    (void)in_sizes; (void)n_in; (void)out_size; (void)ws_size;
    const float* x      = (const float*)d_in[0];
    const float* posm   = (const float*)d_in[1];
    const float* conv_w = (const float*)d_in[2];
    const float* conv_b = (const float*)d_in[3];
    const float* w1     = (const float*)d_in[4];
    const float* b1     = (const float*)d_in[5];
    const float* w2     = (const float*)d_in[6];
    const float* b2     = (const float*)d_in[7];
    float* out = (float*)d_out;

    unsigned short* w2t = (unsigned short*)d_ws;                 // 884736 B
    float* feat = (float*)((char*)d_ws + 884736);                // 16.8 MB

    prep_w2t<<<108, 256, 0, stream>>>(w2, w2t);
    conv5_relu_kernel<<<(NB * G0n * HW * 32) / 256, 256, 0, stream>>>(x, conv_w, conv_b, feat);
    fused_metasr_mfma<<<1024, 256, 0, stream>>>(feat, w2t, posm, w1, b1, b2, out);
}